// Round 1
// baseline (115.730 us; speedup 1.0000x reference)
//
#include <hip/hip_runtime.h>

typedef short v8s __attribute__((ext_vector_type(8)));
typedef float v4f __attribute__((ext_vector_type(4)));

#define CIN   320
#define COUT  320
#define HH    64
#define WW    64
#define BN    64
#define CIB   32
#define XS_C  40     // padded ci stride (elements) -> 80B rows (bank-conflict-free)
#define XCOLS 66     // w = -1 .. 64
#define XROWS 6      // h0-1 .. h0+4

__device__ __forceinline__ float hf8_decode_f(int b) {
    int e = (b >> 3) & 15;
    int m = b & 7;
    // normal: (8+m) * 2^(e-17) ; subnormal: m * 2^-16
    float v = ldexpf((float)(e ? (8 + m) : m), e ? (e - 17) : -16);
    return ((b >> 7) & 1) ? -v : v;
}

__device__ __forceinline__ unsigned short f2bf(float f) {
    unsigned int u = __float_as_uint(f);
    u = (u + 0x7FFFu + ((u >> 16) & 1u)) >> 16;   // round-to-nearest-even
    return (unsigned short)u;
}

// w_bits [Cout][Cin][3][3] i32 -> w_deq [Cout][9][Cin] bf16 ; b_bits -> b_deq f32
__global__ void dequant_kernel(const int* __restrict__ w_bits,
                               const int* __restrict__ b_bits,
                               unsigned short* __restrict__ w_deq,
                               float* __restrict__ b_deq) {
    int idx = blockIdx.x * 256 + threadIdx.x;
    const int total = COUT * 9 * CIN;
    if (idx < total) {
        int co   = idx / (9 * CIN);
        int rem  = idx - co * (9 * CIN);
        int khkw = rem / CIN;
        int ci   = rem - khkw * CIN;
        float v = hf8_decode_f(w_bits[(co * CIN + ci) * 9 + khkw] & 0xFF);
        w_deq[idx] = (unsigned short)(__float_as_uint(v) >> 16);  // exact in bf16
    }
    if (idx < COUT) b_deq[idx] = hf8_decode_f(b_bits[idx] & 0xFF);
}

__global__ __launch_bounds__(256) void conv_mfma_kernel(
        const float* __restrict__ x,
        const unsigned short* __restrict__ w_deq,
        const float* __restrict__ b_deq,
        float* __restrict__ out) {
    __shared__ __align__(16) unsigned short xs[XROWS * XCOLS * XS_C];  // 31680 B
    __shared__ __align__(16) unsigned short wl[BN * 9 * XS_C];         // 46080 B

    const int tid  = threadIdx.x;
    const int bid  = blockIdx.x;
    const int cob  = bid % 5;          // cout block (5 x 64)
    const int mb   = bid / 5;          // 128 m-blocks: 8 images x 16 row-groups
    const int n    = mb >> 4;
    const int h0   = (mb & 15) << 2;   // 4 output rows per block
    const int wave = tid >> 6;         // wave w owns output row h0+w
    const int lane = tid & 63;
    const int lhi  = lane >> 4;
    const int llo  = lane & 15;

    // zero the constant halo columns (global w = -1 and w = 64)
    for (int i = tid; i < XROWS * 2 * XS_C; i += 256) {
        int r  = i / (2 * XS_C);
        int t  = i - r * (2 * XS_C);
        int c  = (t >= XS_C) ? 65 : 0;
        int ci = (t >= XS_C) ? (t - XS_C) : t;
        xs[(r * XCOLS + c) * XS_C + ci] = 0;
    }

    v4f acc[4][4];
    #pragma unroll
    for (int i = 0; i < 4; ++i)
        #pragma unroll
        for (int j = 0; j < 4; ++j)
            acc[i][j] = (v4f){0.f, 0.f, 0.f, 0.f};

    const int ciL2 = tid & 15;   // ci pair index (conflict-free LDS writes)
    const int seg  = tid >> 4;   // 16-byte segment of a row

    for (int ci0 = 0; ci0 < CIN; ci0 += CIB) {
        __syncthreads();
        // ---- stage x: fp32 global -> bf16 LDS [row][col][ci] ----
        {
            const float* xp0 = x + ((size_t)(n * CIN + ci0 + 2 * ciL2)) * (HH * WW);
            const float* xp1 = xp0 + HH * WW;
            #pragma unroll
            for (int r = 0; r < XROWS; ++r) {
                int gh = h0 - 1 + r;
                float4 a = make_float4(0.f, 0.f, 0.f, 0.f);
                float4 b = make_float4(0.f, 0.f, 0.f, 0.f);
                if (gh >= 0 && gh < HH) {
                    a = *(const float4*)(xp0 + gh * WW + seg * 4);
                    b = *(const float4*)(xp1 + gh * WW + seg * 4);
                }
                unsigned int p0 = (unsigned int)f2bf(a.x) | ((unsigned int)f2bf(b.x) << 16);
                unsigned int p1 = (unsigned int)f2bf(a.y) | ((unsigned int)f2bf(b.y) << 16);
                unsigned int p2 = (unsigned int)f2bf(a.z) | ((unsigned int)f2bf(b.z) << 16);
                unsigned int p3 = (unsigned int)f2bf(a.w) | ((unsigned int)f2bf(b.w) << 16);
                int cbase = r * XCOLS + 1 + seg * 4;
                *(unsigned int*)&xs[(cbase + 0) * XS_C + 2 * ciL2] = p0;
                *(unsigned int*)&xs[(cbase + 1) * XS_C + 2 * ciL2] = p1;
                *(unsigned int*)&xs[(cbase + 2) * XS_C + 2 * ciL2] = p2;
                *(unsigned int*)&xs[(cbase + 3) * XS_C + 2 * ciL2] = p3;
            }
        }
        // ---- stage weights: bf16x8 copies, [co][khkw][ci pad 40] ----
        #pragma unroll
        for (int it = 0; it < 9; ++it) {
            int idx  = it * 256 + tid;           // 0..2303 = 64co x 9 x 4cig
            int cig  = idx & 3;
            int rest = idx >> 2;
            int khkw = rest % 9;
            int co   = rest / 9;
            const unsigned short* src =
                w_deq + ((size_t)((cob * BN + co) * 9 + khkw)) * CIN + ci0 + cig * 8;
            int4 v = *(const int4*)src;
            *(int4*)&wl[(co * 9 + khkw) * XS_C + cig * 8] = v;
        }
        __syncthreads();
        // ---- compute: 9 taps x 16 MFMA ----
        #pragma unroll
        for (int khkw = 0; khkw < 9; ++khkw) {
            const int kh = khkw / 3, kw = khkw % 3;
            v8s bfr[4];
            #pragma unroll
            for (int nr = 0; nr < 4; ++nr)
                bfr[nr] = *(const v8s*)&wl[((nr * 16 + llo) * 9 + khkw) * XS_C + lhi * 8];
            #pragma unroll
            for (int mr = 0; mr < 4; ++mr) {
                v8s afr = *(const v8s*)&xs[((wave + kh) * XCOLS + mr * 16 + llo + kw) * XS_C + lhi * 8];
                #pragma unroll
                for (int nr = 0; nr < 4; ++nr)
                    acc[mr][nr] = __builtin_amdgcn_mfma_f32_16x16x32_bf16(
                        afr, bfr[nr], acc[mr][nr], 0, 0, 0);
            }
        }
    }

    // ---- epilogue: bias + float4 stores ----
    const int h = h0 + wave;
    #pragma unroll
    for (int nr = 0; nr < 4; ++nr) {
        int co = cob * BN + nr * 16 + llo;       // D col = lane&15
        float bias = b_deq[co];
        float* op = out + ((size_t)((n * COUT + co) * HH + h)) * WW;
        #pragma unroll
        for (int mr = 0; mr < 4; ++mr) {
            int wc = mr * 16 + lhi * 4;          // D row = (lane>>4)*4 + reg
            float4 o;
            o.x = acc[mr][nr][0] + bias;
            o.y = acc[mr][nr][1] + bias;
            o.z = acc[mr][nr][2] + bias;
            o.w = acc[mr][nr][3] + bias;
            *(float4*)(op + wc) = o;
        }
    }
}

extern "C" void kernel_launch(void* const* d_in, const int* in_sizes, int n_in,
                              void* d_out, int out_size, void* d_ws, size_t ws_size,
                              hipStream_t stream) {
    const float* x      = (const float*)d_in[0];
    const int*   w_bits = (const int*)d_in[1];
    const int*   b_bits = (const int*)d_in[2];
    float*       out    = (float*)d_out;

    unsigned short* w_deq = (unsigned short*)d_ws;                       // 1,843,200 B
    float*          b_deq = (float*)((char*)d_ws + (size_t)COUT * 9 * CIN * 2);

    const int total_w = COUT * 9 * CIN;
    dequant_kernel<<<(total_w + 255) / 256, 256, 0, stream>>>(w_bits, b_bits, w_deq, b_deq);

    // grid: 5 cout-blocks x (8 images x 16 row-groups) = 640 workgroups
    conv_mfma_kernel<<<640, 256, 0, stream>>>(x, w_deq, b_deq, out);
}